// Round 1
// baseline (4177.051 us; speedup 1.0000x reference)
//
#include <hip/hip_runtime.h>
#include <math.h>

constexpr int K_IN  = 1433;
constexpr int HID   = 16;
constexpr int NCLS  = 7;
constexpr int BLK   = 256;
constexpr int CHUNK = 256;   // K-chunk of W1 staged in LDS

__device__ inline float4 wave_reduce4(float4 v) {
#pragma unroll
  for (int off = 32; off > 0; off >>= 1) {
    v.x += __shfl_xor(v.x, off);
    v.y += __shfl_xor(v.y, off);
    v.z += __shfl_xor(v.z, off);
    v.w += __shfl_xor(v.w, off);
  }
  return v;
}

__global__ __launch_bounds__(BLK) void k_init_deg(float* __restrict__ deg, int n) {
  int i = blockIdx.x * BLK + threadIdx.x;
  if (i < n) deg[i] = 1.0f;  // self-loop contributes 1 to every node's degree
}

__global__ __launch_bounds__(BLK) void k_deg_edges(const int* __restrict__ col,
                                                   float* __restrict__ deg, int nE) {
  int e = blockIdx.x * BLK + threadIdx.x;
  if (e < nE) atomicAdd(&deg[col[e]], 1.0f);
}

__global__ __launch_bounds__(BLK) void k_dinv(const float* __restrict__ deg,
                                              float* __restrict__ dinv, int n) {
  int i = blockIdx.x * BLK + threadIdx.x;
  if (i < n) dinv[i] = rsqrtf(deg[i]);
}

// h1 = x @ W1 + b1. One wave computes 2 rows; W1 staged per-256-K-chunk in LDS.
// LDS layout: float4 ws4[k][5] (stride 5 float4 = 20 floats; 16B-aligned b128,
// stride/4 = 5 odd -> 16B-chunk positions (5k+f) mod 8 cover all banks).
__global__ __launch_bounds__(BLK) void k_gemm1(const float* __restrict__ x,
                                               const float* __restrict__ W1,
                                               const float* __restrict__ b1,
                                               float* __restrict__ h1, int n) {
  __shared__ float4 ws4[CHUNK * 5];
  const int lane = threadIdx.x & 63;
  const int wave = threadIdx.x >> 6;
  const int r0 = blockIdx.x * 8 + wave * 2;
  const int r1 = r0 + 1;
  const bool v0 = r0 < n, v1 = r1 < n;
  const float* xr0 = x + (size_t)r0 * K_IN;
  const float* xr1 = x + (size_t)r1 * K_IN;
  float4 a0[4] = {};
  float4 a1[4] = {};

  for (int kc = 0; kc < K_IN; kc += CHUNK) {
    const int kcnt = min(CHUNK, K_IN - kc);
    for (int t = threadIdx.x; t < kcnt * 4; t += BLK) {
      const int kk = t >> 2, j = t & 3;
      ws4[kk * 5 + j] = ((const float4*)W1)[(size_t)(kc + kk) * 4 + j];
    }
    __syncthreads();
#pragma unroll
    for (int j = 0; j < 4; ++j) {
      const int k = kc + j * 64 + lane;
      if (k < K_IN) {
        const int kl = k - kc;
        const float xv0 = v0 ? xr0[k] : 0.0f;
        const float xv1 = v1 ? xr1[k] : 0.0f;
#pragma unroll
        for (int f = 0; f < 4; ++f) {
          const float4 w = ws4[kl * 5 + f];
          a0[f].x = fmaf(xv0, w.x, a0[f].x);
          a0[f].y = fmaf(xv0, w.y, a0[f].y);
          a0[f].z = fmaf(xv0, w.z, a0[f].z);
          a0[f].w = fmaf(xv0, w.w, a0[f].w);
          a1[f].x = fmaf(xv1, w.x, a1[f].x);
          a1[f].y = fmaf(xv1, w.y, a1[f].y);
          a1[f].z = fmaf(xv1, w.z, a1[f].z);
          a1[f].w = fmaf(xv1, w.w, a1[f].w);
        }
      }
    }
    __syncthreads();
  }

#pragma unroll
  for (int f = 0; f < 4; ++f) {
    a0[f] = wave_reduce4(a0[f]);
    a1[f] = wave_reduce4(a1[f]);
  }
  if (lane == 0) {
    const float4* b14 = (const float4*)b1;
    float4* o0 = (float4*)(h1 + (size_t)r0 * HID);
    float4* o1 = (float4*)(h1 + (size_t)r1 * HID);
#pragma unroll
    for (int f = 0; f < 4; ++f) {
      const float4 bb = b14[f];
      if (v0) o0[f] = make_float4(a0[f].x + bb.x, a0[f].y + bb.y, a0[f].z + bb.z, a0[f].w + bb.w);
      if (v1) o1[f] = make_float4(a1[f].x + bb.x, a1[f].y + bb.y, a1[f].z + bb.z, a1[f].w + bb.w);
    }
  }
}

// Per real edge: agg[col] += dinv[row]*dinv[col] * h1[row]  (16 feats)
__global__ __launch_bounds__(BLK) void k_scatter1(const int* __restrict__ row,
                                                  const int* __restrict__ col,
                                                  const float* __restrict__ dinv,
                                                  const float* __restrict__ h1,
                                                  float* __restrict__ agg, int nE) {
  int e = blockIdx.x * BLK + threadIdx.x;
  if (e >= nE) return;
  const int r = row[e], c = col[e];
  const float nrm = dinv[r] * dinv[c];
  const float4* hr = (const float4*)(h1 + (size_t)r * HID);
  float* ac = agg + (size_t)c * HID;
#pragma unroll
  for (int f = 0; f < 4; ++f) {
    const float4 v = hr[f];
    atomicAdd(ac + f * 4 + 0, nrm * v.x);
    atomicAdd(ac + f * 4 + 1, nrm * v.y);
    atomicAdd(ac + f * 4 + 2, nrm * v.z);
    atomicAdd(ac + f * 4 + 3, nrm * v.w);
  }
}

// agg = relu(agg + dinv^2 * h1lin)   (self-loop term fused), elementwise over n*HID
__global__ __launch_bounds__(BLK) void k_finish1(const float* __restrict__ h1,
                                                 const float* __restrict__ dinv,
                                                 float* __restrict__ agg, int n) {
  int idx = blockIdx.x * BLK + threadIdx.x;
  if (idx >= n * HID) return;
  const int node = idx >> 4;
  const float di = dinv[node];
  const float v = agg[idx] + di * di * h1[idx];
  agg[idx] = v > 0.0f ? v : 0.0f;
}

// h2 = h1agg @ W2 + b2  (16 -> 7), one thread per node
__global__ __launch_bounds__(BLK) void k_gemm2(const float* __restrict__ hagg,
                                               const float* __restrict__ W2,
                                               const float* __restrict__ b2,
                                               float* __restrict__ h2, int n) {
  __shared__ float w2s[HID * NCLS];
  __shared__ float b2s[NCLS];
  if (threadIdx.x < HID * NCLS) w2s[threadIdx.x] = W2[threadIdx.x];
  if (threadIdx.x < NCLS) b2s[threadIdx.x] = b2[threadIdx.x];
  __syncthreads();
  int i = blockIdx.x * BLK + threadIdx.x;
  if (i >= n) return;
  float h[HID];
  const float4* hp = (const float4*)(hagg + (size_t)i * HID);
#pragma unroll
  for (int f = 0; f < 4; ++f) {
    const float4 t = hp[f];
    h[f * 4 + 0] = t.x; h[f * 4 + 1] = t.y; h[f * 4 + 2] = t.z; h[f * 4 + 3] = t.w;
  }
  float s[NCLS];
#pragma unroll
  for (int j = 0; j < NCLS; ++j) s[j] = b2s[j];
#pragma unroll
  for (int k = 0; k < HID; ++k) {
#pragma unroll
    for (int j = 0; j < NCLS; ++j) s[j] = fmaf(h[k], w2s[k * NCLS + j], s[j]);
  }
  float* o = h2 + (size_t)i * NCLS;
#pragma unroll
  for (int j = 0; j < NCLS; ++j) o[j] = s[j];
}

__global__ __launch_bounds__(BLK) void k_scatter2(const int* __restrict__ row,
                                                  const int* __restrict__ col,
                                                  const float* __restrict__ dinv,
                                                  const float* __restrict__ h2,
                                                  float* __restrict__ agg2, int nE) {
  int e = blockIdx.x * BLK + threadIdx.x;
  if (e >= nE) return;
  const int r = row[e], c = col[e];
  const float nrm = dinv[r] * dinv[c];
  const float* hr = h2 + (size_t)r * NCLS;
  float* ac = agg2 + (size_t)c * NCLS;
#pragma unroll
  for (int j = 0; j < NCLS; ++j) atomicAdd(ac + j, nrm * hr[j]);
}

// out = log_softmax(relu(agg2 + dinv^2 * h2lin))
__global__ __launch_bounds__(BLK) void k_finish2(const float* __restrict__ h2,
                                                 const float* __restrict__ dinv,
                                                 const float* __restrict__ agg2,
                                                 float* __restrict__ out, int n) {
  int i = blockIdx.x * BLK + threadIdx.x;
  if (i >= n) return;
  const float di = dinv[i];
  const float d2 = di * di;
  const float* a = agg2 + (size_t)i * NCLS;
  const float* l = h2 + (size_t)i * NCLS;
  float v[NCLS];
  float m = 0.0f;  // relu output >= 0
#pragma unroll
  for (int j = 0; j < NCLS; ++j) {
    float t = a[j] + d2 * l[j];
    t = t > 0.0f ? t : 0.0f;
    v[j] = t;
    m = fmaxf(m, t);
  }
  float s = 0.0f;
#pragma unroll
  for (int j = 0; j < NCLS; ++j) s += expf(v[j] - m);
  const float lse = m + logf(s);
  float* o = out + (size_t)i * NCLS;
#pragma unroll
  for (int j = 0; j < NCLS; ++j) o[j] = v[j] - lse;
}

extern "C" void kernel_launch(void* const* d_in, const int* in_sizes, int n_in,
                              void* d_out, int out_size, void* d_ws, size_t ws_size,
                              hipStream_t stream) {
  const float* x  = (const float*)d_in[0];
  const float* W1 = (const float*)d_in[1];
  const float* b1 = (const float*)d_in[2];
  const float* W2 = (const float*)d_in[3];
  const float* b2 = (const float*)d_in[4];
  const int*   ei = (const int*)d_in[5];

  const int n  = in_sizes[0] / K_IN;       // 100000
  const int nE = in_sizes[5] / 2;          // 3200000
  const int* row = ei;                     // edge_index[0]
  const int* col = ei + nE;                // edge_index[1]

  float* ws = (float*)d_ws;
  float* deg    = ws;                        // n
  float* dinv   = ws + (size_t)n;            // n
  float* h1lin  = ws + (size_t)2 * n;        // n*16
  float* h1agg  = ws + (size_t)18 * n;       // n*16
  float* h2lin  = ws + (size_t)34 * n;       // n*7
  float* agg2   = ws + (size_t)41 * n;       // n*7

  const int gN   = (n + BLK - 1) / BLK;            // node-wise
  const int gE   = (nE + BLK - 1) / BLK;           // edge-wise
  const int gEl1 = (n * HID + BLK - 1) / BLK;      // elementwise n*16
  const int gG1  = (n + 7) / 8;                    // gemm1: 8 rows/block

  // degrees (self-loops folded in as init=1)
  k_init_deg<<<gN, BLK, 0, stream>>>(deg, n);
  k_deg_edges<<<gE, BLK, 0, stream>>>(col, deg, nE);
  k_dinv<<<gN, BLK, 0, stream>>>(deg, dinv, n);

  // layer 1
  k_gemm1<<<gG1, BLK, 0, stream>>>(x, W1, b1, h1lin, n);
  hipMemsetAsync(h1agg, 0, (size_t)n * HID * sizeof(float), stream);
  k_scatter1<<<gE, BLK, 0, stream>>>(row, col, dinv, h1lin, h1agg, nE);
  k_finish1<<<gEl1, BLK, 0, stream>>>(h1lin, dinv, h1agg, n);

  // layer 2
  k_gemm2<<<gN, BLK, 0, stream>>>(h1agg, W2, b2, h2lin, n);
  hipMemsetAsync(agg2, 0, (size_t)n * NCLS * sizeof(float), stream);
  k_scatter2<<<gE, BLK, 0, stream>>>(row, col, dinv, h2lin, agg2, nE);
  k_finish2<<<gN, BLK, 0, stream>>>(h2lin, dinv, agg2, (float*)d_out, n);
}

// Round 2
// 755.576 us; speedup vs baseline: 5.5283x; 5.5283x over previous
//
#include <hip/hip_runtime.h>
#include <math.h>

constexpr int K_IN  = 1433;
constexpr int HID   = 16;
constexpr int NCLS  = 7;
constexpr int BLK   = 256;
constexpr int CHUNK = 256;   // K-chunk of W1 staged in LDS

__device__ inline float4 wave_reduce4(float4 v) {
#pragma unroll
  for (int off = 32; off > 0; off >>= 1) {
    v.x += __shfl_xor(v.x, off);
    v.y += __shfl_xor(v.y, off);
    v.z += __shfl_xor(v.z, off);
    v.w += __shfl_xor(v.w, off);
  }
  return v;
}

// ---- CSR build ---------------------------------------------------------

__global__ __launch_bounds__(BLK) void k_count(const int* __restrict__ col,
                                               int* __restrict__ cnt, int nE) {
  int e = blockIdx.x * BLK + threadIdx.x;
  if (e < nE) atomicAdd(&cnt[col[e]], 1);
}

__global__ __launch_bounds__(BLK) void k_dinv(const int* __restrict__ cnt,
                                              float* __restrict__ dinv, int n) {
  int i = blockIdx.x * BLK + threadIdx.x;
  if (i < n) dinv[i] = rsqrtf((float)(cnt[i] + 1));  // +1 = self loop
}

// exclusive scan of cnt[0..n) -> start[0..n), single 1024-thread block
__global__ __launch_bounds__(1024) void k_scan(const int* __restrict__ cnt,
                                               int* __restrict__ start, int n) {
  __shared__ int wsum[16];
  __shared__ int carry;
  const int lane = threadIdx.x & 63;
  const int w = threadIdx.x >> 6;
  if (threadIdx.x == 0) carry = 0;
  __syncthreads();
  for (int base = 0; base < n; base += 1024) {
    const int i = base + threadIdx.x;
    const int c = (i < n) ? cnt[i] : 0;
    int s = c;  // inclusive wave scan
#pragma unroll
    for (int off = 1; off < 64; off <<= 1) {
      int t = __shfl_up(s, off);
      if (lane >= off) s += t;
    }
    if (lane == 63) wsum[w] = s;
    __syncthreads();                       // wsum ready
    if (w == 0 && lane < 16) {
      int ws = wsum[lane];
#pragma unroll
      for (int off = 1; off < 16; off <<= 1) {
        int t = __shfl_up(ws, off, 16);
        if (lane >= off) ws += t;
      }
      wsum[lane] = ws;                     // inclusive wave-sum scan
    }
    __syncthreads();                       // wsum scanned
    const int woff = (w > 0) ? wsum[w - 1] : 0;
    if (i < n) start[i] = carry + woff + s - c;
    __syncthreads();                       // all done reading carry/wsum
    if (threadIdx.x == 0) carry += wsum[15];
    __syncthreads();                       // carry updated before next iter
  }
}

// edata[p] = {row, norm} sorted into per-col segments
__global__ __launch_bounds__(BLK) void k_fill(const int* __restrict__ row,
                                              const int* __restrict__ col,
                                              const int* __restrict__ start,
                                              int* __restrict__ cursor,
                                              const float* __restrict__ dinv,
                                              int2* __restrict__ edata, int nE) {
  int e = blockIdx.x * BLK + threadIdx.x;
  if (e >= nE) return;
  const int r = row[e], c = col[e];
  const int p = start[c] + atomicAdd(&cursor[c], 1);
  edata[p] = make_int2(r, __float_as_int(dinv[r] * dinv[c]));
}

// ---- layer compute -----------------------------------------------------

// h1 = x @ W1 + b1. One wave computes 2 rows; W1 staged per-256-K-chunk in LDS.
__global__ __launch_bounds__(BLK) void k_gemm1(const float* __restrict__ x,
                                               const float* __restrict__ W1,
                                               const float* __restrict__ b1,
                                               float* __restrict__ h1, int n) {
  __shared__ float4 ws4[CHUNK * 5];
  const int lane = threadIdx.x & 63;
  const int wave = threadIdx.x >> 6;
  const int r0 = blockIdx.x * 8 + wave * 2;
  const int r1 = r0 + 1;
  const bool v0 = r0 < n, v1 = r1 < n;
  const float* xr0 = x + (size_t)r0 * K_IN;
  const float* xr1 = x + (size_t)r1 * K_IN;
  float4 a0[4] = {};
  float4 a1[4] = {};

  for (int kc = 0; kc < K_IN; kc += CHUNK) {
    const int kcnt = min(CHUNK, K_IN - kc);
    for (int t = threadIdx.x; t < kcnt * 4; t += BLK) {
      const int kk = t >> 2, j = t & 3;
      ws4[kk * 5 + j] = ((const float4*)W1)[(size_t)(kc + kk) * 4 + j];
    }
    __syncthreads();
#pragma unroll
    for (int j = 0; j < 4; ++j) {
      const int k = kc + j * 64 + lane;
      if (k < K_IN) {
        const int kl = k - kc;
        const float xv0 = v0 ? xr0[k] : 0.0f;
        const float xv1 = v1 ? xr1[k] : 0.0f;
#pragma unroll
        for (int f = 0; f < 4; ++f) {
          const float4 w = ws4[kl * 5 + f];
          a0[f].x = fmaf(xv0, w.x, a0[f].x);
          a0[f].y = fmaf(xv0, w.y, a0[f].y);
          a0[f].z = fmaf(xv0, w.z, a0[f].z);
          a0[f].w = fmaf(xv0, w.w, a0[f].w);
          a1[f].x = fmaf(xv1, w.x, a1[f].x);
          a1[f].y = fmaf(xv1, w.y, a1[f].y);
          a1[f].z = fmaf(xv1, w.z, a1[f].z);
          a1[f].w = fmaf(xv1, w.w, a1[f].w);
        }
      }
    }
    __syncthreads();
  }

#pragma unroll
  for (int f = 0; f < 4; ++f) {
    a0[f] = wave_reduce4(a0[f]);
    a1[f] = wave_reduce4(a1[f]);
  }
  if (lane == 0) {
    const float4* b14 = (const float4*)b1;
    float4* o0 = (float4*)(h1 + (size_t)r0 * HID);
    float4* o1 = (float4*)(h1 + (size_t)r1 * HID);
#pragma unroll
    for (int f = 0; f < 4; ++f) {
      const float4 bb = b14[f];
      if (v0) o0[f] = make_float4(a0[f].x + bb.x, a0[f].y + bb.y, a0[f].z + bb.z, a0[f].w + bb.w);
      if (v1) o1[f] = make_float4(a1[f].x + bb.x, a1[f].y + bb.y, a1[f].z + bb.z, a1[f].w + bb.w);
    }
  }
}

// gather layer 1: 16 threads per node, 16 nodes per block.
// h1agg[i][f] = relu( dinv[i]^2*h1[i][f] + sum_seg norm*h1[row][f] )
__global__ __launch_bounds__(BLK) void k_gather1(const int2* __restrict__ edata,
                                                 const int* __restrict__ start,
                                                 const int* __restrict__ cnt,
                                                 const float* __restrict__ dinv,
                                                 const float* __restrict__ h1,
                                                 float* __restrict__ h1agg, int n) {
  const int i = blockIdx.x * 16 + (threadIdx.x >> 4);
  const int f = threadIdx.x & 15;
  if (i >= n) return;
  const float di = dinv[i];
  float acc = di * di * h1[(size_t)i * HID + f];  // self loop
  const int s = start[i];
  const int end = s + cnt[i];
  int p = s;
  for (; p + 1 < end; p += 2) {
    const int2 e0 = edata[p];
    const int2 e1 = edata[p + 1];
    const float v0 = h1[(size_t)e0.x * HID + f];
    const float v1 = h1[(size_t)e1.x * HID + f];
    acc = fmaf(__int_as_float(e0.y), v0, acc);
    acc = fmaf(__int_as_float(e1.y), v1, acc);
  }
  if (p < end) {
    const int2 e0 = edata[p];
    acc = fmaf(__int_as_float(e0.y), h1[(size_t)e0.x * HID + f], acc);
  }
  h1agg[(size_t)i * HID + f] = acc > 0.0f ? acc : 0.0f;
}

// h2 = h1agg @ W2 + b2  (16 -> 7), one thread per node
__global__ __launch_bounds__(BLK) void k_gemm2(const float* __restrict__ hagg,
                                               const float* __restrict__ W2,
                                               const float* __restrict__ b2,
                                               float* __restrict__ h2, int n) {
  __shared__ float w2s[HID * NCLS];
  __shared__ float b2s[NCLS];
  if (threadIdx.x < HID * NCLS) w2s[threadIdx.x] = W2[threadIdx.x];
  if (threadIdx.x < NCLS) b2s[threadIdx.x] = b2[threadIdx.x];
  __syncthreads();
  int i = blockIdx.x * BLK + threadIdx.x;
  if (i >= n) return;
  float h[HID];
  const float4* hp = (const float4*)(hagg + (size_t)i * HID);
#pragma unroll
  for (int f = 0; f < 4; ++f) {
    const float4 t = hp[f];
    h[f * 4 + 0] = t.x; h[f * 4 + 1] = t.y; h[f * 4 + 2] = t.z; h[f * 4 + 3] = t.w;
  }
  float s[NCLS];
#pragma unroll
  for (int j = 0; j < NCLS; ++j) s[j] = b2s[j];
#pragma unroll
  for (int k = 0; k < HID; ++k) {
#pragma unroll
    for (int j = 0; j < NCLS; ++j) s[j] = fmaf(h[k], w2s[k * NCLS + j], s[j]);
  }
  float* o = h2 + (size_t)i * NCLS;
#pragma unroll
  for (int j = 0; j < NCLS; ++j) o[j] = s[j];
}

// gather layer 2 + log_softmax: 8 threads per node (f<7 active), 32 nodes/block
__global__ __launch_bounds__(BLK) void k_gather2(const int2* __restrict__ edata,
                                                 const int* __restrict__ start,
                                                 const int* __restrict__ cnt,
                                                 const float* __restrict__ dinv,
                                                 const float* __restrict__ h2,
                                                 float* __restrict__ out, int n) {
  const int i = blockIdx.x * 32 + (threadIdx.x >> 3);
  const int f = threadIdx.x & 7;
  if (i >= n) return;
  const bool act = f < NCLS;
  const float di = dinv[i];
  float acc = act ? di * di * h2[(size_t)i * NCLS + f] : 0.0f;  // self loop
  const int s = start[i];
  const int end = s + cnt[i];
  int p = s;
  for (; p + 1 < end; p += 2) {
    const int2 e0 = edata[p];
    const int2 e1 = edata[p + 1];
    if (act) {
      acc = fmaf(__int_as_float(e0.y), h2[(size_t)e0.x * NCLS + f], acc);
      acc = fmaf(__int_as_float(e1.y), h2[(size_t)e1.x * NCLS + f], acc);
    }
  }
  if (p < end) {
    const int2 e0 = edata[p];
    if (act) acc = fmaf(__int_as_float(e0.y), h2[(size_t)e0.x * NCLS + f], acc);
  }
  // relu
  const float t = acc > 0.0f ? acc : 0.0f;
  // max over the 8-lane group (lane 7 contributes -inf)
  float tm = act ? t : -1e30f;
#pragma unroll
  for (int off = 1; off < 8; off <<= 1) tm = fmaxf(tm, __shfl_xor(tm, off, 8));
  // sum of exp (lane 7 contributes 0)
  float se = act ? __expf(t - tm) : 0.0f;
#pragma unroll
  for (int off = 1; off < 8; off <<= 1) se += __shfl_xor(se, off, 8);
  const float lse = tm + __logf(se);
  if (act) out[(size_t)i * NCLS + f] = t - lse;
}

extern "C" void kernel_launch(void* const* d_in, const int* in_sizes, int n_in,
                              void* d_out, int out_size, void* d_ws, size_t ws_size,
                              hipStream_t stream) {
  const float* x  = (const float*)d_in[0];
  const float* W1 = (const float*)d_in[1];
  const float* b1 = (const float*)d_in[2];
  const float* W2 = (const float*)d_in[3];
  const float* b2 = (const float*)d_in[4];
  const int*   ei = (const int*)d_in[5];

  const int n  = in_sizes[0] / K_IN;       // 100000
  const int nE = in_sizes[5] / 2;          // 3200000
  const int* row = ei;                     // edge_index[0] (source)
  const int* col = ei + nE;                // edge_index[1] (target)

  // workspace layout (bytes): all 4-byte elements
  char* w = (char*)d_ws;
  int*   cnt    = (int*)w;                        w += (size_t)n * 4;
  int*   start  = (int*)w;                        w += (size_t)n * 4;
  int*   cursor = (int*)w;                        w += (size_t)n * 4;
  float* dinv   = (float*)w;                      w += (size_t)n * 4;
  float* h1lin  = (float*)w;                      w += (size_t)n * HID * 4;
  float* h1agg  = (float*)w;                      w += (size_t)n * HID * 4;
  float* h2lin  = (float*)w;                      w += (size_t)n * NCLS * 4;
  int2*  edata  = (int2*)w;                       w += (size_t)nE * 8;

  const int gN = (n + BLK - 1) / BLK;
  const int gE = (nE + BLK - 1) / BLK;
  const int gG1 = (n + 7) / 8;          // gemm1: 8 rows/block
  const int gGa1 = (n + 15) / 16;       // gather1: 16 nodes/block
  const int gGa2 = (n + 31) / 32;       // gather2: 32 nodes/block

  // CSR build (shared by both layers)
  hipMemsetAsync(cnt, 0, (size_t)n * 4, stream);
  hipMemsetAsync(cursor, 0, (size_t)n * 4, stream);
  k_count<<<gE, BLK, 0, stream>>>(col, cnt, nE);
  k_dinv<<<gN, BLK, 0, stream>>>(cnt, dinv, n);
  k_scan<<<1, 1024, 0, stream>>>(cnt, start, n);
  k_fill<<<gE, BLK, 0, stream>>>(row, col, start, cursor, dinv, edata, nE);

  // layer 1
  k_gemm1<<<gG1, BLK, 0, stream>>>(x, W1, b1, h1lin, n);
  k_gather1<<<gGa1, BLK, 0, stream>>>(edata, start, cnt, dinv, h1lin, h1agg, n);

  // layer 2
  k_gemm2<<<gN, BLK, 0, stream>>>(h1agg, W2, b2, h2lin, n);
  k_gather2<<<gGa2, BLK, 0, stream>>>(edata, start, cnt, dinv, h2lin, (float*)d_out, n);
}

// Round 3
// 690.238 us; speedup vs baseline: 6.0516x; 1.0947x over previous
//
#include <hip/hip_runtime.h>
#include <math.h>

constexpr int K_IN  = 1433;
constexpr int HID   = 16;
constexpr int NCLS  = 7;
constexpr int BLK   = 256;
constexpr int CHUNK = 256;   // K-chunk of W1 staged in LDS

__device__ inline float4 wave_reduce4(float4 v) {
#pragma unroll
  for (int off = 32; off > 0; off >>= 1) {
    v.x += __shfl_xor(v.x, off);
    v.y += __shfl_xor(v.y, off);
    v.z += __shfl_xor(v.z, off);
    v.w += __shfl_xor(v.w, off);
  }
  return v;
}

// ---- CSR build ---------------------------------------------------------

__global__ __launch_bounds__(BLK) void k_zero(int* __restrict__ p, int n) {
  int i = blockIdx.x * BLK + threadIdx.x;
  if (i < n) p[i] = 0;
}

__global__ __launch_bounds__(BLK) void k_count(const int* __restrict__ col,
                                               int* __restrict__ cnt, int nE) {
  int e = blockIdx.x * BLK + threadIdx.x;
  if (e < nE) atomicAdd(&cnt[col[e]], 1);
}

__global__ __launch_bounds__(BLK) void k_dinv(const int* __restrict__ cnt,
                                              float* __restrict__ dinv, int n) {
  int i = blockIdx.x * BLK + threadIdx.x;
  if (i < n) dinv[i] = rsqrtf((float)(cnt[i] + 1));  // +1 = self loop
}

// exclusive scan of cnt[0..n) -> start AND cursor, single 1024-thread block,
// 4 elements/thread via int4 (offsets 16B-padded by the allocator).
__global__ __launch_bounds__(1024) void k_scan(const int* __restrict__ cnt,
                                               int* __restrict__ start,
                                               int* __restrict__ cursor, int n) {
  __shared__ int wsum[16];
  __shared__ int carry;
  const int lane = threadIdx.x & 63;
  const int w = threadIdx.x >> 6;
  if (threadIdx.x == 0) carry = 0;
  __syncthreads();
  const int n4 = n >> 2;  // full int4s
  for (int base = 0; base < n4; base += 1024) {
    const int i4 = base + threadIdx.x;
    int4 c = make_int4(0, 0, 0, 0);
    if (i4 < n4) c = ((const int4*)cnt)[i4];
    const int tsum = c.x + c.y + c.z + c.w;
    int s = tsum;  // inclusive wave scan of per-thread sums
#pragma unroll
    for (int off = 1; off < 64; off <<= 1) {
      int t = __shfl_up(s, off);
      if (lane >= off) s += t;
    }
    if (lane == 63) wsum[w] = s;
    __syncthreads();                       // wsum ready
    if (w == 0 && lane < 16) {
      int ws = wsum[lane];
#pragma unroll
      for (int off = 1; off < 16; off <<= 1) {
        int t = __shfl_up(ws, off, 16);
        if (lane >= off) ws += t;
      }
      wsum[lane] = ws;                     // inclusive wave-sum scan
    }
    __syncthreads();                       // wsum scanned
    if (i4 < n4) {
      const int woff = (w > 0) ? wsum[w - 1] : 0;
      const int b = carry + woff + s - tsum;
      int4 o;
      o.x = b;
      o.y = b + c.x;
      o.z = o.y + c.y;
      o.w = o.z + c.z;
      ((int4*)start)[i4] = o;
      ((int4*)cursor)[i4] = o;
    }
    __syncthreads();                       // everyone done with carry/wsum
    if (threadIdx.x == 0) carry += wsum[15];
    __syncthreads();
  }
  if (threadIdx.x == 0) {                  // scalar tail if n % 4 != 0
    int b = carry;
    for (int i = n4 << 2; i < n; ++i) { start[i] = b; cursor[i] = b; b += cnt[i]; }
  }
}

// edata[p] = {row, norm} sorted into per-col segments; cursor pre-init = start
__global__ __launch_bounds__(BLK) void k_fill(const int* __restrict__ row,
                                              const int* __restrict__ col,
                                              int* __restrict__ cursor,
                                              const float* __restrict__ dinv,
                                              int2* __restrict__ edata, int nE) {
  int e = blockIdx.x * BLK + threadIdx.x;
  if (e >= nE) return;
  const int r = row[e], c = col[e];
  const int p = atomicAdd(&cursor[c], 1);
  edata[p] = make_int2(r, __float_as_int(dinv[r] * dinv[c]));
}

// ---- layer compute -----------------------------------------------------

// h1 = x @ W1 + b1. One wave computes 2 rows; W1 staged per-256-K-chunk in LDS.
__global__ __launch_bounds__(BLK) void k_gemm1(const float* __restrict__ x,
                                               const float* __restrict__ W1,
                                               const float* __restrict__ b1,
                                               float* __restrict__ h1, int n) {
  __shared__ float4 ws4[CHUNK * 5];
  const int lane = threadIdx.x & 63;
  const int wave = threadIdx.x >> 6;
  const int r0 = blockIdx.x * 8 + wave * 2;
  const int r1 = r0 + 1;
  const bool v0 = r0 < n, v1 = r1 < n;
  const float* xr0 = x + (size_t)r0 * K_IN;
  const float* xr1 = x + (size_t)r1 * K_IN;
  float4 a0[4] = {};
  float4 a1[4] = {};

  for (int kc = 0; kc < K_IN; kc += CHUNK) {
    const int kcnt = min(CHUNK, K_IN - kc);
    for (int t = threadIdx.x; t < kcnt * 4; t += BLK) {
      const int kk = t >> 2, j = t & 3;
      ws4[kk * 5 + j] = ((const float4*)W1)[(size_t)(kc + kk) * 4 + j];
    }
    __syncthreads();
#pragma unroll
    for (int j = 0; j < 4; ++j) {
      const int k = kc + j * 64 + lane;
      if (k < K_IN) {
        const int kl = k - kc;
        const float xv0 = v0 ? xr0[k] : 0.0f;
        const float xv1 = v1 ? xr1[k] : 0.0f;
#pragma unroll
        for (int f = 0; f < 4; ++f) {
          const float4 w = ws4[kl * 5 + f];
          a0[f].x = fmaf(xv0, w.x, a0[f].x);
          a0[f].y = fmaf(xv0, w.y, a0[f].y);
          a0[f].z = fmaf(xv0, w.z, a0[f].z);
          a0[f].w = fmaf(xv0, w.w, a0[f].w);
          a1[f].x = fmaf(xv1, w.x, a1[f].x);
          a1[f].y = fmaf(xv1, w.y, a1[f].y);
          a1[f].z = fmaf(xv1, w.z, a1[f].z);
          a1[f].w = fmaf(xv1, w.w, a1[f].w);
        }
      }
    }
    __syncthreads();
  }

#pragma unroll
  for (int f = 0; f < 4; ++f) {
    a0[f] = wave_reduce4(a0[f]);
    a1[f] = wave_reduce4(a1[f]);
  }
  if (lane == 0) {
    const float4* b14 = (const float4*)b1;
    float4* o0 = (float4*)(h1 + (size_t)r0 * HID);
    float4* o1 = (float4*)(h1 + (size_t)r1 * HID);
#pragma unroll
    for (int f = 0; f < 4; ++f) {
      const float4 bb = b14[f];
      if (v0) o0[f] = make_float4(a0[f].x + bb.x, a0[f].y + bb.y, a0[f].z + bb.z, a0[f].w + bb.w);
      if (v1) o1[f] = make_float4(a1[f].x + bb.x, a1[f].y + bb.y, a1[f].z + bb.z, a1[f].w + bb.w);
    }
  }
}

// gather layer 1: 16 threads per node, 16 nodes per block.
// h1agg[i][f] = relu( dinv[i]^2*h1[i][f] + sum_seg norm*h1[row][f] )
__global__ __launch_bounds__(BLK) void k_gather1(const int2* __restrict__ edata,
                                                 const int* __restrict__ start,
                                                 const int* __restrict__ cnt,
                                                 const float* __restrict__ dinv,
                                                 const float* __restrict__ h1,
                                                 float* __restrict__ h1agg, int n) {
  const int i = blockIdx.x * 16 + (threadIdx.x >> 4);
  const int f = threadIdx.x & 15;
  if (i >= n) return;
  const float di = dinv[i];
  float acc = di * di * h1[(size_t)i * HID + f];  // self loop
  const int s = start[i];
  const int end = s + cnt[i];
  int p = s;
  for (; p + 1 < end; p += 2) {
    const int2 e0 = edata[p];
    const int2 e1 = edata[p + 1];
    const float v0 = h1[(size_t)e0.x * HID + f];
    const float v1 = h1[(size_t)e1.x * HID + f];
    acc = fmaf(__int_as_float(e0.y), v0, acc);
    acc = fmaf(__int_as_float(e1.y), v1, acc);
  }
  if (p < end) {
    const int2 e0 = edata[p];
    acc = fmaf(__int_as_float(e0.y), h1[(size_t)e0.x * HID + f], acc);
  }
  h1agg[(size_t)i * HID + f] = acc > 0.0f ? acc : 0.0f;
}

// h2 = h1agg @ W2 + b2  (16 -> 7), one thread per node
__global__ __launch_bounds__(BLK) void k_gemm2(const float* __restrict__ hagg,
                                               const float* __restrict__ W2,
                                               const float* __restrict__ b2,
                                               float* __restrict__ h2, int n) {
  __shared__ float w2s[HID * NCLS];
  __shared__ float b2s[NCLS];
  if (threadIdx.x < HID * NCLS) w2s[threadIdx.x] = W2[threadIdx.x];
  if (threadIdx.x < NCLS) b2s[threadIdx.x] = b2[threadIdx.x];
  __syncthreads();
  int i = blockIdx.x * BLK + threadIdx.x;
  if (i >= n) return;
  float h[HID];
  const float4* hp = (const float4*)(hagg + (size_t)i * HID);
#pragma unroll
  for (int f = 0; f < 4; ++f) {
    const float4 t = hp[f];
    h[f * 4 + 0] = t.x; h[f * 4 + 1] = t.y; h[f * 4 + 2] = t.z; h[f * 4 + 3] = t.w;
  }
  float s[NCLS];
#pragma unroll
  for (int j = 0; j < NCLS; ++j) s[j] = b2s[j];
#pragma unroll
  for (int k = 0; k < HID; ++k) {
#pragma unroll
    for (int j = 0; j < NCLS; ++j) s[j] = fmaf(h[k], w2s[k * NCLS + j], s[j]);
  }
  float* o = h2 + (size_t)i * NCLS;
#pragma unroll
  for (int j = 0; j < NCLS; ++j) o[j] = s[j];
}

// gather layer 2 + log_softmax: 8 threads per node (f<7 active), 32 nodes/block
__global__ __launch_bounds__(BLK) void k_gather2(const int2* __restrict__ edata,
                                                 const int* __restrict__ start,
                                                 const int* __restrict__ cnt,
                                                 const float* __restrict__ dinv,
                                                 const float* __restrict__ h2,
                                                 float* __restrict__ out, int n) {
  const int i = blockIdx.x * 32 + (threadIdx.x >> 3);
  const int f = threadIdx.x & 7;
  if (i >= n) return;
  const bool act = f < NCLS;
  const float di = dinv[i];
  float acc = act ? di * di * h2[(size_t)i * NCLS + f] : 0.0f;  // self loop
  const int s = start[i];
  const int end = s + cnt[i];
  int p = s;
  for (; p + 1 < end; p += 2) {
    const int2 e0 = edata[p];
    const int2 e1 = edata[p + 1];
    if (act) {
      acc = fmaf(__int_as_float(e0.y), h2[(size_t)e0.x * NCLS + f], acc);
      acc = fmaf(__int_as_float(e1.y), h2[(size_t)e1.x * NCLS + f], acc);
    }
  }
  if (p < end) {
    const int2 e0 = edata[p];
    if (act) acc = fmaf(__int_as_float(e0.y), h2[(size_t)e0.x * NCLS + f], acc);
  }
  const float t = acc > 0.0f ? acc : 0.0f;  // relu
  float tm = act ? t : -1e30f;
#pragma unroll
  for (int off = 1; off < 8; off <<= 1) tm = fmaxf(tm, __shfl_xor(tm, off, 8));
  float se = act ? __expf(t - tm) : 0.0f;
#pragma unroll
  for (int off = 1; off < 8; off <<= 1) se += __shfl_xor(se, off, 8);
  const float lse = tm + __logf(se);
  if (act) out[(size_t)i * NCLS + f] = t - lse;
}

extern "C" void kernel_launch(void* const* d_in, const int* in_sizes, int n_in,
                              void* d_out, int out_size, void* d_ws, size_t ws_size,
                              hipStream_t stream) {
  const float* x  = (const float*)d_in[0];
  const float* W1 = (const float*)d_in[1];
  const float* b1 = (const float*)d_in[2];
  const float* W2 = (const float*)d_in[3];
  const float* b2 = (const float*)d_in[4];
  const int*   ei = (const int*)d_in[5];

  const int n  = in_sizes[0] / K_IN;       // 100000
  const int nE = in_sizes[5] / 2;          // 3200000
  const int* row = ei;                     // edge_index[0] (source)
  const int* col = ei + nE;                // edge_index[1] (target)

  // workspace layout, every block 16B-aligned
  char* w = (char*)d_ws;
  size_t off = 0;
  auto alloc = [&](size_t elems) {
    void* p = w + off;
    off += ((elems * 4 + 15) & ~(size_t)15);
    return p;
  };
  int*   cnt    = (int*)alloc(n);
  int*   start  = (int*)alloc(n);
  int*   cursor = (int*)alloc(n);
  float* dinv   = (float*)alloc(n);
  float* h1lin  = (float*)alloc((size_t)n * HID);
  float* h1agg  = (float*)alloc((size_t)n * HID);
  float* h2lin  = (float*)alloc((size_t)n * NCLS);
  int2*  edata  = (int2*)alloc((size_t)nE * 2);

  const int gN = (n + BLK - 1) / BLK;
  const int gE = (nE + BLK - 1) / BLK;
  const int gG1 = (n + 7) / 8;          // gemm1: 8 rows/block
  const int gGa1 = (n + 15) / 16;       // gather1: 16 nodes/block
  const int gGa2 = (n + 31) / 32;       // gather2: 32 nodes/block

  // CSR build (shared by both layers) — no memset nodes in the graph
  k_zero<<<gN, BLK, 0, stream>>>(cnt, n);
  k_count<<<gE, BLK, 0, stream>>>(col, cnt, nE);
  k_dinv<<<gN, BLK, 0, stream>>>(cnt, dinv, n);
  k_scan<<<1, 1024, 0, stream>>>(cnt, start, cursor, n);
  k_fill<<<gE, BLK, 0, stream>>>(row, col, cursor, dinv, edata, nE);

  // layer 1
  k_gemm1<<<gG1, BLK, 0, stream>>>(x, W1, b1, h1lin, n);
  k_gather1<<<gGa1, BLK, 0, stream>>>(edata, start, cnt, dinv, h1lin, h1agg, n);

  // layer 2
  k_gemm2<<<gN, BLK, 0, stream>>>(h1agg, W2, b2, h2lin, n);
  k_gather2<<<gGa2, BLK, 0, stream>>>(edata, start, cnt, dinv, h2lin, (float*)d_out, n);
}